// Round 11
// baseline (11874.490 us; speedup 1.0000x reference)
//
#include <hip/hip_runtime.h>
#include <cstddef>

#define B      64
#define IC     1152
#define CH     512
#define SPLITS 16     // A-phase i-splits; IC/SPLITS = 72 rows per tile
#define GRID   1024   // persistent grid: 4 blocks/CU x 256 CUs
#define NT     256

// ---------------- reduction helpers ----------------

__device__ __forceinline__ float waveReduceSum(float v) {
    #pragma unroll
    for (int o = 32; o; o >>= 1) v += __shfl_down(v, o, 64);
    return v;
}
__device__ __forceinline__ float waveReduceMax(float v) {
    #pragma unroll
    for (int o = 32; o; o >>= 1) v = fmaxf(v, __shfl_down(v, o, 64));
    return v;
}

template<int NTT>
__device__ __forceinline__ float blockReduceSum(float v, float* red) {
    __syncthreads();
    const int lane = threadIdx.x & 63, w = threadIdx.x >> 6;
    v = waveReduceSum(v);
    if (lane == 0) red[w] = v;
    __syncthreads();
    if (threadIdx.x == 0) {
        float t = red[0];
        #pragma unroll
        for (int k = 1; k < NTT / 64; ++k) t += red[k];
        red[0] = t;
    }
    __syncthreads();
    return red[0];
}

template<int NTT>
__device__ __forceinline__ float blockReduceMax(float v, float* red) {
    __syncthreads();
    const int lane = threadIdx.x & 63, w = threadIdx.x >> 6;
    v = waveReduceMax(v);
    if (lane == 0) red[w] = v;
    __syncthreads();
    if (threadIdx.x == 0) {
        float t = red[0];
        #pragma unroll
        for (int k = 1; k < NTT / 64; ++k) t = fmaxf(t, red[k]);
        red[0] = t;
    }
    __syncthreads();
    return red[0];
}

// bf16 pack (RNE) / unpack
__device__ __forceinline__ unsigned bfpack2(float a, float b) {
    unsigned ua = __float_as_uint(a), ub = __float_as_uint(b);
    ua = (ua + 0x7FFFu + ((ua >> 16) & 1u)) >> 16;
    ub = (ub + 0x7FFFu + ((ub >> 16) & 1u)) & 0xFFFF0000u;
    return ua | ub;
}
__device__ __forceinline__ void bfunpack2(unsigned u, float& lo, float& hi) {
    lo = __uint_as_float(u << 16);
    hi = __uint_as_float(u & 0xFFFF0000u);
}

// ---------------- device-wide barrier (sense via generation counter) ----------------
// bar[0] = arrival count, bar[16] = generation (separate 64B lines).
// Co-residency of all GRID blocks is guaranteed by __launch_bounds__(256,4):
// 4 waves/EU -> 4 blocks/CU x 256 CUs = 1024 = GRID.
__device__ __forceinline__ void gsync(unsigned* bar) {
    __threadfence();            // publish this thread's global writes (agent scope)
    __syncthreads();
    if (threadIdx.x == 0) {
        unsigned* cnt = bar;
        unsigned* gen = bar + 16;
        unsigned g = __hip_atomic_load(gen, __ATOMIC_RELAXED, __HIP_MEMORY_SCOPE_AGENT);
        unsigned old = __hip_atomic_fetch_add(cnt, 1u, __ATOMIC_ACQ_REL, __HIP_MEMORY_SCOPE_AGENT);
        if (old + 1u == (unsigned)GRID) {
            __hip_atomic_store(cnt, 0u, __ATOMIC_RELAXED, __HIP_MEMORY_SCOPE_AGENT);
            __hip_atomic_fetch_add(gen, 1u, __ATOMIC_RELEASE, __HIP_MEMORY_SCOPE_AGENT);
        } else {
            while (__hip_atomic_load(gen, __ATOMIC_ACQUIRE, __HIP_MEMORY_SCOPE_AGENT) == g)
                __builtin_amdgcn_s_sleep(2);
        }
    }
    __syncthreads();
    __threadfence();            // discard stale cached lines before post-barrier reads
}

// ---------------- persistent kernel: setup + 10 routing iterations + output ----------------

__global__ __launch_bounds__(NT, 4) void k_persist(
    const float* __restrict__ x, const float* __restrict__ W,
    const float* __restrict__ bias, const float* __restrict__ coeffs,
    float* __restrict__ out, unsigned* __restrict__ bar,
    uint4* __restrict__ xbf, float* __restrict__ WWT, float* __restrict__ Wb,
    float* __restrict__ bb, float* __restrict__ cvec, float* __restrict__ Wv,
    float* __restrict__ xcpart)
{
    __shared__ float eS[IC];
    __shared__ float accS[3][CH];
    __shared__ float xcS[CH];
    __shared__ float red[4];
    const int bid = blockIdx.x, tid = threadIdx.x;

    // ======== setup phase ========
    // (1) convert x -> bf16, 4608 uint4 per block
    {
        const size_t base = (size_t)bid * 4608 + tid;
        const float4* xp4 = reinterpret_cast<const float4*>(x);
        #pragma unroll 2
        for (int k = 0; k < 18; ++k) {
            size_t idx = base + (size_t)k * 256;
            float4 a = xp4[idx * 2], b2 = xp4[idx * 2 + 1];
            uint4 o;
            o.x = bfpack2(a.x, a.y); o.y = bfpack2(a.z, a.w);
            o.z = bfpack2(b2.x, b2.y); o.w = bfpack2(b2.z, b2.w);
            xbf[idx] = o;
        }
    }
    // (2) WWT 16x16 tile per block: WWT[a][c2] = dot(W[a,:], W[c2,:])
    {
        const int ta = bid >> 5, tc = bid & 31;
        const int a = ta * 16 + (tid >> 4), c2 = tc * 16 + (tid & 15);
        const float* ra = W + (size_t)a * CH;
        const float* rc = W + (size_t)c2 * CH;
        float s = 0;
        for (int j = 0; j < CH; ++j) s += ra[j] * rc[j];
        WWT[(size_t)a * CH + c2] = s;
    }
    // (3) Wb (blocks 0-1), bb (block 2), cvec init (blocks 3-7)
    if (bid < 2) {
        int c = bid * 256 + tid;
        const float* rw = W + (size_t)c * CH;
        float s = 0;
        for (int j = 0; j < CH; ++j) s += rw[j] * bias[j];
        Wb[c] = s;
    } else if (bid == 2) {
        float v0 = bias[tid], v1 = bias[tid + 256];
        float n2 = blockReduceSum<NT>(v0 * v0 + v1 * v1, red);
        if (tid == 0) *bb = n2;
    } else if (bid >= 3 && bid < 8) {
        int i = (bid - 3) * 256 + tid;
        if (i < IC) cvec[i] = coeffs[i];
    }
    gsync(bar);

    // ======== routing iterations ========
    for (int t = 0; t < 10; ++t) {
        // ---- phase A: xcpart[is][b][:] = (1/Z) sum_{i in slice} e_i * x[b,i,:] ----
        {
            const int b = bid >> 4, is = bid & 15;
            // block-local softmax over cvec
            float cl[5];
            float m = -3.4e38f;
            #pragma unroll
            for (int k = 0; k < 5; ++k) {
                int i = tid + k * 256;
                cl[k] = (i < IC) ? cvec[i] : -3.4e38f;
                m = fmaxf(m, cl[k]);
            }
            float M = blockReduceMax<NT>(m, red);
            float z = 0;
            #pragma unroll
            for (int k = 0; k < 5; ++k) {
                int i = tid + k * 256;
                if (i < IC) { float e = expf(cl[k] - M); eS[i] = e; z += e; }
            }
            float Z = blockReduceSum<NT>(z, red);
            const float invZ = 1.0f / Z;

            const int rp = tid >> 6, c8 = tid & 63;
            const int i0 = is * (IC / SPLITS);
            float acc[8];
            #pragma unroll
            for (int e = 0; e < 8; ++e) acc[e] = 0.f;
            const uint4* xp = xbf + ((size_t)(b * IC + i0 + rp)) * (CH / 8) + c8;
            #pragma unroll 2
            for (int k = 0; k < IC / SPLITS / 4; ++k) {
                float w = eS[i0 + rp + 4 * k];
                uint4 u = xp[(size_t)k * 4 * (CH / 8)];
                float f0, f1;
                bfunpack2(u.x, f0, f1); acc[0] += w * f0; acc[1] += w * f1;
                bfunpack2(u.y, f0, f1); acc[2] += w * f0; acc[3] += w * f1;
                bfunpack2(u.z, f0, f1); acc[4] += w * f0; acc[5] += w * f1;
                bfunpack2(u.w, f0, f1); acc[6] += w * f0; acc[7] += w * f1;
            }
            if (rp > 0) {
                #pragma unroll
                for (int e = 0; e < 8; ++e) accS[rp - 1][c8 * 8 + e] = acc[e];
            }
            __syncthreads();
            if (rp == 0) {
                float4 o0, o1;
                #pragma unroll
                for (int e = 0; e < 8; ++e) {
                    float v = acc[e] + accS[0][c8 * 8 + e] + accS[1][c8 * 8 + e] + accS[2][c8 * 8 + e];
                    if (e < 4) reinterpret_cast<float*>(&o0)[e] = v * invZ;
                    else       reinterpret_cast<float*>(&o1)[e - 4] = v * invZ;
                }
                float4* outp = reinterpret_cast<float4*>(xcpart + ((size_t)(is * B + b)) * CH) + c8 * 2;
                outp[0] = o0;
                outp[1] = o1;
            }
        }
        gsync(bar);
        if (t == 9) break;

        // ---- phase core (blocks < 64): Wv[b] = g * (WWT*xc + Wb) ----
        if (bid < 64) {
            const int b = bid;
            for (int c = tid; c < CH; c += 256) {
                float s = 0;
                #pragma unroll
                for (int is2 = 0; is2 < SPLITS; ++is2)
                    s += xcpart[((size_t)(is2 * B + b)) * CH + c];
                xcS[c] = s;
            }
            __syncthreads();
            const int c0 = tid, c1 = tid + 256;
            float h0 = 0, h1 = 0;
            for (int cp = 0; cp < CH; ++cp) {
                float xv = xcS[cp];
                h0 += xv * WWT[(size_t)cp * CH + c0];
                h1 += xv * WWT[(size_t)cp * CH + c1];
            }
            float xv0 = xcS[c0], xv1 = xcS[c1];
            float part = xv0 * h0 + xv1 * h1 + 2.0f * (Wb[c0] * xv0 + Wb[c1] * xv1);
            float tot = blockReduceSum<NT>(part, red);
            float n2 = tot + *bb;
            float n = sqrtf(n2);
            float g = n / (1.0f + n2);
            Wv[(size_t)b * CH + c0] = g * (h0 + Wb[c0]);
            Wv[(size_t)b * CH + c1] = g * (h1 + Wb[c1]);
        }
        gsync(bar);

        // ---- phase C: cvec[i] += sum_{b,c} x[b,i,c] * Wv[b,c] ----
        for (int i = bid; i < IC; i += GRID) {
            const int bp = tid >> 6, c8 = tid & 63;
            float acc = 0;
            #pragma unroll 2
            for (int k = 0; k < B / 4; ++k) {
                int b = bp + 4 * k;
                uint4 u = xbf[((size_t)(b * IC + i)) * (CH / 8) + c8];
                const float4* wvp = reinterpret_cast<const float4*>(Wv + (size_t)b * CH) + c8 * 2;
                float4 w0 = wvp[0], w1 = wvp[1];
                float f0, f1;
                bfunpack2(u.x, f0, f1); acc += f0 * w0.x + f1 * w0.y;
                bfunpack2(u.y, f0, f1); acc += f0 * w0.z + f1 * w0.w;
                bfunpack2(u.z, f0, f1); acc += f0 * w1.x + f1 * w1.y;
                bfunpack2(u.w, f0, f1); acc += f0 * w1.z + f1 * w1.w;
            }
            float tot = blockReduceSum<NT>(acc, red);
            if (tid == 0) cvec[i] += tot;
        }
        gsync(bar);
    }

    // ======== final: s = xc*W + bias ; out = s*||s||/(1+||s||^2) ========
    if (bid < 64) {
        const int b = bid;
        for (int c = tid; c < CH; c += 256) {
            float s = 0;
            #pragma unroll
            for (int is2 = 0; is2 < SPLITS; ++is2)
                s += xcpart[((size_t)(is2 * B + b)) * CH + c];
            xcS[c] = s;
        }
        __syncthreads();
        const int j0 = tid, j1 = tid + 256;
        float s0 = bias[j0], s1 = bias[j1];
        for (int c = 0; c < CH; ++c) {
            float xv = xcS[c];
            s0 += xv * W[(size_t)c * CH + j0];
            s1 += xv * W[(size_t)c * CH + j1];
        }
        float n2 = blockReduceSum<NT>(s0 * s0 + s1 * s1, red);
        float n = sqrtf(n2);
        float g = n / (1.0f + n2);
        out[(size_t)b * CH + j0] = s0 * g;
        out[(size_t)b * CH + j1] = s1 * g;
    }
}

// ---------------- fp32 fallback (round-1 validated, used only if ws too small) ----------------

__global__ __launch_bounds__(1024) void k_transpose(const float* __restrict__ W,
                                                    float* __restrict__ WT) {
    __shared__ float tile[32][33];
    int x = blockIdx.x * 32 + threadIdx.x;
    int y = blockIdx.y * 32 + threadIdx.y;
    tile[threadIdx.y][threadIdx.x] = W[(size_t)y * CH + x];
    __syncthreads();
    int tx = blockIdx.y * 32 + threadIdx.x;
    int ty = blockIdx.x * 32 + threadIdx.y;
    WT[(size_t)ty * CH + tx] = tile[threadIdx.x][threadIdx.y];
}

__global__ __launch_bounds__(256) void k_wwt(const float* __restrict__ W,
                                             const float* __restrict__ WT,
                                             float* __restrict__ WWT) {
    __shared__ float wa[2][CH];
    const int a0 = blockIdx.x * 2;
    for (int j = threadIdx.x; j < CH; j += 256) {
        wa[0][j] = W[(size_t)a0 * CH + j];
        wa[1][j] = W[(size_t)(a0 + 1) * CH + j];
    }
    __syncthreads();
    const int c0 = threadIdx.x, c1 = threadIdx.x + 256;
    float a00 = 0, a01 = 0, a10 = 0, a11 = 0;
    for (int j = 0; j < CH; ++j) {
        float w0 = wa[0][j], w1 = wa[1][j];
        float t0 = WT[(size_t)j * CH + c0], t1 = WT[(size_t)j * CH + c1];
        a00 += w0 * t0; a01 += w0 * t1;
        a10 += w1 * t0; a11 += w1 * t1;
    }
    WWT[(size_t)a0 * CH + c0] = a00;
    WWT[(size_t)a0 * CH + c1] = a01;
    WWT[(size_t)(a0 + 1) * CH + c0] = a10;
    WWT[(size_t)(a0 + 1) * CH + c1] = a11;
}

__global__ __launch_bounds__(512) void k_wb(const float* __restrict__ WT,
                                            const float* __restrict__ bias,
                                            float* __restrict__ Wb,
                                            float* __restrict__ bb) {
    __shared__ float bS[CH];
    __shared__ float red[8];
    const int c = threadIdx.x;
    bS[c] = bias[c];
    __syncthreads();
    float acc = 0;
    for (int j = 0; j < CH; ++j) acc += bS[j] * WT[(size_t)j * CH + c];
    Wb[c] = acc;
    float n2 = blockReduceSum<512>(bS[c] * bS[c], red);
    if (c == 0) *bb = n2;
}

__global__ void k_init(const float* __restrict__ coeffs, float* __restrict__ cvec) {
    int i = blockIdx.x * 256 + threadIdx.x;
    if (i < IC) cvec[i] = coeffs[i];
}

__global__ __launch_bounds__(256) void k_passA_f32(const float* __restrict__ x,
                                                   const float* __restrict__ cvec,
                                                   float* __restrict__ xcpart) {
    __shared__ float eS[IC];
    __shared__ float red[4];
    const int b = blockIdx.x, is = blockIdx.y;
    const int t = threadIdx.x;
    float cl[5];
    float m = -3.4e38f;
    #pragma unroll
    for (int k = 0; k < 5; ++k) {
        int i = t + k * 256;
        cl[k] = (i < IC) ? cvec[i] : -3.4e38f;
        m = fmaxf(m, cl[k]);
    }
    float M = blockReduceMax<256>(m, red);
    float z = 0;
    #pragma unroll
    for (int k = 0; k < 5; ++k) {
        int i = t + k * 256;
        if (i < IC) { float e = expf(cl[k] - M); eS[i] = e; z += e; }
    }
    float Z = blockReduceSum<256>(z, red);
    const float invZ = 1.0f / Z;
    const int i0 = is * (IC / SPLITS);
    float2 acc = make_float2(0.f, 0.f);
    const float2* xp = reinterpret_cast<const float2*>(x + ((size_t)b * IC + i0) * CH) + t;
    #pragma unroll 4
    for (int i = i0; i < i0 + IC / SPLITS; ++i) {
        float w = eS[i];
        float2 xv = *xp;
        acc.x += w * xv.x;
        acc.y += w * xv.y;
        xp += CH / 2;
    }
    float2* outp = reinterpret_cast<float2*>(xcpart + ((size_t)(is * B + b)) * CH) + t;
    *outp = make_float2(acc.x * invZ, acc.y * invZ);
}

__global__ __launch_bounds__(1024) void k_core_f(const float* __restrict__ xcpart,
                                                 const float* __restrict__ WWT,
                                                 const float* __restrict__ Wb,
                                                 const float* __restrict__ bbp,
                                                 float* __restrict__ Wv) {
    __shared__ float xcS[CH];
    __shared__ float hS[CH];
    __shared__ float red[16];
    __shared__ float gS;
    const int b = blockIdx.x, tid = threadIdx.x;
    const int c = tid & (CH - 1), half = tid >> 9;
    if (half == 0) {
        float s = 0;
        #pragma unroll
        for (int is = 0; is < SPLITS; ++is) s += xcpart[((size_t)(is * B + b)) * CH + c];
        xcS[c] = s;
    }
    __syncthreads();
    float acc = 0;
    const int cp0 = half * (CH / 2);
    for (int cp = cp0; cp < cp0 + CH / 2; ++cp)
        acc += xcS[cp] * WWT[(size_t)cp * CH + c];
    if (half == 0) hS[c] = acc;
    __syncthreads();
    if (half == 1) hS[c] += acc;
    __syncthreads();
    float part = 0;
    if (half == 0) {
        float xcv = xcS[c];
        part = xcv * hS[c] + 2.0f * Wb[c] * xcv;
    }
    float tot = blockReduceSum<1024>(part, red);
    if (tid == 0) {
        float n2 = tot + *bbp;
        float n = sqrtf(n2);
        gS = n / (1.0f + n2);
    }
    __syncthreads();
    if (half == 0) Wv[(size_t)b * CH + c] = gS * (hS[c] + Wb[c]);
}

__global__ __launch_bounds__(256) void k_passC_f32(const float* __restrict__ x,
                                                   const float* __restrict__ Wv,
                                                   float* __restrict__ cvec) {
    __shared__ float red[4];
    const int i = blockIdx.x, t = threadIdx.x;
    float acc = 0;
    const float2* wvp = reinterpret_cast<const float2*>(Wv) + t;
    const float2* xp = reinterpret_cast<const float2*>(x) + (size_t)i * (CH / 2) + t;
    #pragma unroll 4
    for (int b = 0; b < B; ++b) {
        float2 xv = xp[(size_t)b * IC * (CH / 2)];
        float2 wv = wvp[(size_t)b * (CH / 2)];
        acc += xv.x * wv.x + xv.y * wv.y;
    }
    float tot = blockReduceSum<256>(acc, red);
    if (t == 0) cvec[i] += tot;
}

__global__ __launch_bounds__(512) void k_final_f(const float* __restrict__ xcpart,
                                                 const float* __restrict__ W,
                                                 const float* __restrict__ bias,
                                                 float* __restrict__ out) {
    __shared__ float xcS[CH];
    __shared__ float red[8];
    __shared__ float gS;
    const int b = blockIdx.x, j = threadIdx.x;
    float s = 0;
    #pragma unroll
    for (int is = 0; is < SPLITS; ++is) s += xcpart[((size_t)(is * B + b)) * CH + j];
    xcS[j] = s;
    __syncthreads();
    float sj = bias[j];
    for (int c = 0; c < CH; ++c) sj += xcS[c] * W[(size_t)c * CH + j];
    float n2 = blockReduceSum<512>(sj * sj, red);
    if (j == 0) { float n = sqrtf(n2); gS = n / (1.0f + n2); }
    __syncthreads();
    out[(size_t)b * CH + j] = sj * gS;
}

// ---------------- launch ----------------

extern "C" void kernel_launch(void* const* d_in, const int* in_sizes, int n_in,
                              void* d_out, int out_size, void* d_ws, size_t ws_size,
                              hipStream_t stream) {
    (void)in_sizes; (void)n_in; (void)out_size;
    const float* x      = (const float*)d_in[0];   // [64,1152,512]
    const float* W      = (const float*)d_in[1];   // [512,512]  (in,out)
    const float* bias   = (const float*)d_in[2];   // [512]
    const float* coeffs = (const float*)d_in[3];   // [1,1152,1]
    float* out = (float*)d_out;

    const size_t xbf_bytes = (size_t)B * IC * CH * 2;   // 75.5 MB
    // layout (fast): [0..255] barrier | xbf | fp32 scratch (~3.3 MB)
    const size_t f32_floats = 262144 + 512 + 16 + 1152 + 32768 + 524288 + 64;
    const bool fast = ws_size >= 256 + xbf_bytes + f32_floats * 4 + 256;

    if (fast) {
        unsigned* bar = (unsigned*)d_ws;
        uint4* xbf = (uint4*)((char*)d_ws + 256);
        float* ws  = (float*)((char*)d_ws + 256 + xbf_bytes);
        float* WWT    = ws;                 // 262144
        float* Wb     = ws + 262144;        // 512
        float* bb     = ws + 262656;        // 16
        float* cvec   = ws + 262672;        // 1152
        float* Wv     = ws + 263824;        // 32768
        float* xcpart = ws + 296592;        // 524288

        hipMemsetAsync(d_ws, 0, 256, stream);   // zero barrier cnt/gen
        k_persist<<<GRID, NT, 0, stream>>>(x, W, bias, coeffs, out, bar,
                                           xbf, WWT, Wb, bb, cvec, Wv, xcpart);
    } else {
        float* ws = (float*)d_ws;
        float* WT     = ws;              // 262144
        float* WWT    = ws + 262144;     // 262144
        float* Wb     = ws + 524288;     // 512
        float* bb     = ws + 524800;     // 16
        float* cvec   = ws + 524816;     // 1152
        float* Wv     = ws + 525968;     // 32768
        float* xcpart = ws + 558736;     // 524288

        k_transpose<<<dim3(16, 16), dim3(32, 32), 0, stream>>>(W, WT);
        k_wwt<<<256, 256, 0, stream>>>(W, WT, WWT);
        k_wb<<<1, 512, 0, stream>>>(WT, bias, Wb, bb);
        k_init<<<5, 256, 0, stream>>>(coeffs, cvec);
        for (int t = 0; t < 9; ++t) {
            k_passA_f32<<<dim3(B, SPLITS), 256, 0, stream>>>(x, cvec, xcpart);
            k_core_f<<<B, 1024, 0, stream>>>(xcpart, WWT, Wb, bb, Wv);
            k_passC_f32<<<IC, 256, 0, stream>>>(x, Wv, cvec);
        }
        k_passA_f32<<<dim3(B, SPLITS), 256, 0, stream>>>(x, cvec, xcpart);
        k_final_f<<<B, 512, 0, stream>>>(xcpart, W, bias, out);
    }
}

// Round 13
// 2008.792 us; speedup vs baseline: 5.9113x; 5.9113x over previous
//
#include <hip/hip_runtime.h>
#include <cstddef>

#define B      64
#define IC     1152
#define CH     512
#define NCVT   2048   // setup blocks doing fp32->bf16 conversion

// ---------------- reduction helpers ----------------

__device__ __forceinline__ float waveReduceSum(float v) {
    #pragma unroll
    for (int o = 32; o; o >>= 1) v += __shfl_down(v, o, 64);
    return v;
}
__device__ __forceinline__ float waveReduceMax(float v) {
    #pragma unroll
    for (int o = 32; o; o >>= 1) v = fmaxf(v, __shfl_down(v, o, 64));
    return v;
}

template<int NTT>
__device__ __forceinline__ float blockReduceSum(float v, float* red) {
    __syncthreads();
    const int lane = threadIdx.x & 63, w = threadIdx.x >> 6;
    v = waveReduceSum(v);
    if (lane == 0) red[w] = v;
    __syncthreads();
    if (threadIdx.x == 0) {
        float t = red[0];
        #pragma unroll
        for (int k = 1; k < NTT / 64; ++k) t += red[k];
        red[0] = t;
    }
    __syncthreads();
    return red[0];
}

template<int NTT>
__device__ __forceinline__ float blockReduceMax(float v, float* red) {
    __syncthreads();
    const int lane = threadIdx.x & 63, w = threadIdx.x >> 6;
    v = waveReduceMax(v);
    if (lane == 0) red[w] = v;
    __syncthreads();
    if (threadIdx.x == 0) {
        float t = red[0];
        #pragma unroll
        for (int k = 1; k < NTT / 64; ++k) t = fmaxf(t, red[k]);
        red[0] = t;
    }
    __syncthreads();
    return red[0];
}

// bf16 pack (RNE) / unpack
__device__ __forceinline__ unsigned bfpack2(float a, float b) {
    unsigned ua = __float_as_uint(a), ub = __float_as_uint(b);
    ua = (ua + 0x7FFFu + ((ua >> 16) & 1u)) >> 16;
    ub = (ub + 0x7FFFu + ((ub >> 16) & 1u)) & 0xFFFF0000u;
    return ua | ub;
}
__device__ __forceinline__ void bfunpack2(unsigned u, float& lo, float& hi) {
    lo = __uint_as_float(u << 16);
    hi = __uint_as_float(u & 0xFFFF0000u);
}

// ---------------- fused setup: cvt + WWT + Wb + bb + buffer init ----------------
// grid = NCVT + 1024 + 3 blocks, 256 threads each. bufs = [10][IC] floats.

__global__ __launch_bounds__(256) void k_setup(
    const float* __restrict__ x, const float* __restrict__ W,
    const float* __restrict__ bias, const float* __restrict__ coeffs,
    uint4* __restrict__ xbf, float* __restrict__ WWT, float* __restrict__ Wb,
    float* __restrict__ bb, float* __restrict__ bufs)
{
    __shared__ float red[4];
    const int bid = blockIdx.x, tid = threadIdx.x;

    if (bid < NCVT) {
        // fp32 -> bf16, 9 uint4 per thread; NCVT*256*9 = 4718592 = B*IC*CH/8 exactly
        const size_t base = (size_t)bid * (256 * 9) + tid;
        const float4* xp4 = reinterpret_cast<const float4*>(x);
        #pragma unroll 3
        for (int k = 0; k < 9; ++k) {
            size_t idx = base + (size_t)k * 256;
            float4 a = xp4[idx * 2], b2 = xp4[idx * 2 + 1];
            uint4 o;
            o.x = bfpack2(a.x, a.y); o.y = bfpack2(a.z, a.w);
            o.z = bfpack2(b2.x, b2.y); o.w = bfpack2(b2.z, b2.w);
            xbf[idx] = o;
        }
    } else if (bid < NCVT + 1024) {
        // WWT 16x16 tile per block (validated round 11)
        const int bidw = bid - NCVT;
        const int ta = bidw >> 5, tc = bidw & 31;
        const int a = ta * 16 + (tid >> 4), c2 = tc * 16 + (tid & 15);
        const float* ra = W + (size_t)a * CH;
        const float* rc = W + (size_t)c2 * CH;
        float s = 0;
        for (int j = 0; j < CH; ++j) s += ra[j] * rc[j];
        WWT[(size_t)a * CH + c2] = s;
    } else if (bid == NCVT + 1024) {
        // Wb[c] = dot(W[c,:], bias), 2 rows per thread (validated round 11)
        #pragma unroll
        for (int r = 0; r < 2; ++r) {
            int c = tid + r * 256;
            const float* rw = W + (size_t)c * CH;
            float s = 0;
            for (int j = 0; j < CH; ++j) s += rw[j] * bias[j];
            Wb[c] = s;
        }
    } else if (bid == NCVT + 1025) {
        // bb = ||bias||^2
        float v0 = bias[tid], v1 = bias[tid + 256];
        float n2 = blockReduceSum<256>(v0 * v0 + v1 * v1, red);
        if (tid == 0) *bb = n2;
    } else {
        // buf0 = coeffs ; bufs 1..9 = 0
        for (int i = tid; i < IC; i += 256) bufs[i] = coeffs[i];
        for (int k = tid; k < 9 * IC; k += 256) bufs[IC + k] = 0.f;
    }
}

// ---------------- per-iteration kernel: one block per batch element ----------------
// block b: softmax(cin) -> w ; xc_b = X_b^T w ; h = WWT xc ; g ; Wv = g(h+Wb) ;
// upd_partial = X_b Wv ; atomicAdd into cout. Block 0 also adds cin into cout.

__global__ __launch_bounds__(1024) void k_iter(
    const uint4* __restrict__ xbf, const float* __restrict__ WWT,
    const float* __restrict__ Wb, const float* __restrict__ bbp,
    const float* __restrict__ cin, float* __restrict__ cout)
{
    __shared__ float eS[IC];
    __shared__ float accS[15][CH];
    __shared__ float xcS[CH];
    __shared__ float hS[CH];
    __shared__ float WvS[CH];
    __shared__ float red[16];
    __shared__ float gS;
    const int b = blockIdx.x, tid = threadIdx.x;

    // ---- softmax over cin (redundant per block; cheap) ----
    float c0v = cin[tid];
    float c1v = (tid < IC - 1024) ? cin[tid + 1024] : -3.4e38f;
    float M = blockReduceMax<1024>(fmaxf(c0v, c1v), red);
    float e0 = expf(c0v - M);
    float e1 = (tid < IC - 1024) ? expf(c1v - M) : 0.f;
    eS[tid] = e0;
    if (tid < IC - 1024) eS[tid + 1024] = e1;
    float Z = blockReduceSum<1024>(e0 + e1, red);
    const float invZ = 1.0f / Z;

    // ---- phase 2: xc_b[c] = invZ * sum_i e_i * x[b,i,c] ----
    const int rp = tid >> 6;      // 0..15 row parity
    const int c8 = tid & 63;      // uint4 column group
    float acc[8];
    #pragma unroll
    for (int e = 0; e < 8; ++e) acc[e] = 0.f;
    {
        const uint4* xp = xbf + ((size_t)b * IC + rp) * (CH / 8) + c8;
        for (int i = rp; i < IC; i += 16) {
            float w = eS[i];
            uint4 u = *xp; xp += 16 * (CH / 8);
            float f0, f1;
            bfunpack2(u.x, f0, f1); acc[0] += w * f0; acc[1] += w * f1;
            bfunpack2(u.y, f0, f1); acc[2] += w * f0; acc[3] += w * f1;
            bfunpack2(u.z, f0, f1); acc[4] += w * f0; acc[5] += w * f1;
            bfunpack2(u.w, f0, f1); acc[6] += w * f0; acc[7] += w * f1;
        }
    }
    if (rp > 0) {
        #pragma unroll
        for (int e = 0; e < 8; ++e) accS[rp - 1][c8 * 8 + e] = acc[e];
    }
    __syncthreads();
    if (rp == 0) {
        #pragma unroll
        for (int e = 0; e < 8; ++e) {
            float v = acc[e];
            #pragma unroll
            for (int k = 0; k < 15; ++k) v += accS[k][c8 * 8 + e];
            xcS[c8 * 8 + e] = v * invZ;
        }
    }
    __syncthreads();

    // ---- phase 3: h = WWT*xc ; n2 = xc.h + 2 Wb.xc + bb ; g ; Wv ----
    const int cc = tid & (CH - 1), half = tid >> 9;
    float hp = 0;
    {
        const int cp0 = half * (CH / 2);
        for (int cp = cp0; cp < cp0 + CH / 2; ++cp)
            hp += xcS[cp] * WWT[(size_t)cp * CH + cc];
    }
    if (half == 1) hS[cc] = hp;
    __syncthreads();
    float part = 0;
    if (half == 0) {
        float h = hp + hS[cc];
        hS[cc] = h;
        float xv = xcS[cc];
        part = xv * h + 2.0f * Wb[cc] * xv;
    }
    float tot = blockReduceSum<1024>(part, red);
    if (tid == 0) {
        float n2 = tot + *bbp;
        float n = sqrtf(n2);
        gS = n / (1.0f + n2);
    }
    __syncthreads();
    if (half == 0) WvS[cc] = gS * (hS[cc] + Wb[cc]);
    __syncthreads();

    // ---- phase 4: upd_i += x[b,i,:].Wv ; atomic into cout ----
    {
        const float4* wv4 = reinterpret_cast<const float4*>(WvS) + c8 * 2;
        float4 w0 = wv4[0], w1 = wv4[1];
        const uint4* xq = xbf + ((size_t)b * IC + rp) * (CH / 8) + c8;
        for (int i = rp; i < IC; i += 16) {
            uint4 u = *xq; xq += 16 * (CH / 8);
            float f0, f1, s = 0;
            bfunpack2(u.x, f0, f1); s += f0 * w0.x + f1 * w0.y;
            bfunpack2(u.y, f0, f1); s += f0 * w0.z + f1 * w0.w;
            bfunpack2(u.z, f0, f1); s += f0 * w1.x + f1 * w1.y;
            bfunpack2(u.w, f0, f1); s += f0 * w1.z + f1 * w1.w;
            s = waveReduceSum(s);
            if (c8 == 0) atomicAdd(cout + i, s);
        }
    }
    // carry base cvec into next buffer (once)
    if (b == 0) {
        for (int i = tid; i < IC; i += 1024) atomicAdd(cout + i, cin[i]);
    }
}

// ---------------- final: v = squash(xc.W + bias) ----------------

__global__ __launch_bounds__(1024) void k_final(
    const uint4* __restrict__ xbf, const float* __restrict__ W,
    const float* __restrict__ bias, const float* __restrict__ cin,
    float* __restrict__ out)
{
    __shared__ float eS[IC];
    __shared__ float accS[15][CH];
    __shared__ float xcS[CH];
    __shared__ float hS[CH];
    __shared__ float red[16];
    __shared__ float gS;
    const int b = blockIdx.x, tid = threadIdx.x;

    float c0v = cin[tid];
    float c1v = (tid < IC - 1024) ? cin[tid + 1024] : -3.4e38f;
    float M = blockReduceMax<1024>(fmaxf(c0v, c1v), red);
    float e0 = expf(c0v - M);
    float e1 = (tid < IC - 1024) ? expf(c1v - M) : 0.f;
    eS[tid] = e0;
    if (tid < IC - 1024) eS[tid + 1024] = e1;
    float Z = blockReduceSum<1024>(e0 + e1, red);
    const float invZ = 1.0f / Z;

    const int rp = tid >> 6, c8 = tid & 63;
    float acc[8];
    #pragma unroll
    for (int e = 0; e < 8; ++e) acc[e] = 0.f;
    {
        const uint4* xp = xbf + ((size_t)b * IC + rp) * (CH / 8) + c8;
        for (int i = rp; i < IC; i += 16) {
            float w = eS[i];
            uint4 u = *xp; xp += 16 * (CH / 8);
            float f0, f1;
            bfunpack2(u.x, f0, f1); acc[0] += w * f0; acc[1] += w * f1;
            bfunpack2(u.y, f0, f1); acc[2] += w * f0; acc[3] += w * f1;
            bfunpack2(u.z, f0, f1); acc[4] += w * f0; acc[5] += w * f1;
            bfunpack2(u.w, f0, f1); acc[6] += w * f0; acc[7] += w * f1;
        }
    }
    if (rp > 0) {
        #pragma unroll
        for (int e = 0; e < 8; ++e) accS[rp - 1][c8 * 8 + e] = acc[e];
    }
    __syncthreads();
    if (rp == 0) {
        #pragma unroll
        for (int e = 0; e < 8; ++e) {
            float v = acc[e];
            #pragma unroll
            for (int k = 0; k < 15; ++k) v += accS[k][c8 * 8 + e];
            xcS[c8 * 8 + e] = v * invZ;
        }
    }
    __syncthreads();

    // s_j = xc.W[:,j] + bias_j  (coalesced over j)
    const int j = tid & (CH - 1), half = tid >> 9;
    float sp = 0;
    {
        const int cp0 = half * (CH / 2);
        for (int cp = cp0; cp < cp0 + CH / 2; ++cp)
            sp += xcS[cp] * W[(size_t)cp * CH + j];
    }
    if (half == 1) hS[j] = sp;
    __syncthreads();
    float part = 0;
    if (half == 0) {
        float s = sp + hS[j] + bias[j];
        hS[j] = s;
        part = s * s;
    }
    float tot = blockReduceSum<1024>(part, red);
    if (tid == 0) {
        float n = sqrtf(tot);
        gS = n / (1.0f + tot);
    }
    __syncthreads();
    if (half == 0) out[(size_t)b * CH + j] = hS[j] * gS;
}

// ---------------- fp32 fallback (round-1 validated; only if ws too small) ----------------

#define SPLITS 16

__global__ __launch_bounds__(1024) void k_transpose(const float* __restrict__ W,
                                                    float* __restrict__ WT) {
    __shared__ float tile[32][33];
    int x = blockIdx.x * 32 + threadIdx.x;
    int y = blockIdx.y * 32 + threadIdx.y;
    tile[threadIdx.y][threadIdx.x] = W[(size_t)y * CH + x];
    __syncthreads();
    int tx = blockIdx.y * 32 + threadIdx.x;
    int ty = blockIdx.x * 32 + threadIdx.y;
    WT[(size_t)ty * CH + tx] = tile[threadIdx.x][threadIdx.y];
}

__global__ __launch_bounds__(256) void k_wwt_f(const float* __restrict__ W,
                                               const float* __restrict__ WT,
                                               float* __restrict__ WWT) {
    __shared__ float wa[2][CH];
    const int a0 = blockIdx.x * 2;
    for (int j = threadIdx.x; j < CH; j += 256) {
        wa[0][j] = W[(size_t)a0 * CH + j];
        wa[1][j] = W[(size_t)(a0 + 1) * CH + j];
    }
    __syncthreads();
    const int c0 = threadIdx.x, c1 = threadIdx.x + 256;
    float a00 = 0, a01 = 0, a10 = 0, a11 = 0;
    for (int j = 0; j < CH; ++j) {
        float w0 = wa[0][j], w1 = wa[1][j];
        float t0 = WT[(size_t)j * CH + c0], t1 = WT[(size_t)j * CH + c1];
        a00 += w0 * t0; a01 += w0 * t1;
        a10 += w1 * t0; a11 += w1 * t1;
    }
    WWT[(size_t)a0 * CH + c0] = a00;
    WWT[(size_t)a0 * CH + c1] = a01;
    WWT[(size_t)(a0 + 1) * CH + c0] = a10;
    WWT[(size_t)(a0 + 1) * CH + c1] = a11;
}

__global__ __launch_bounds__(512) void k_wb_f(const float* __restrict__ WT,
                                              const float* __restrict__ bias,
                                              float* __restrict__ Wb,
                                              float* __restrict__ bb) {
    __shared__ float bS[CH];
    __shared__ float red[8];
    const int c = threadIdx.x;
    bS[c] = bias[c];
    __syncthreads();
    float acc = 0;
    for (int j = 0; j < CH; ++j) acc += bS[j] * WT[(size_t)j * CH + c];
    Wb[c] = acc;
    float n2 = blockReduceSum<512>(bS[c] * bS[c], red);
    if (c == 0) *bb = n2;
}

__global__ void k_init_f(const float* __restrict__ coeffs, float* __restrict__ cvec) {
    int i = blockIdx.x * 256 + threadIdx.x;
    if (i < IC) cvec[i] = coeffs[i];
}

__global__ __launch_bounds__(256) void k_passA_f32(const float* __restrict__ x,
                                                   const float* __restrict__ cvec,
                                                   float* __restrict__ xcpart) {
    __shared__ float eS[IC];
    __shared__ float red[4];
    const int b = blockIdx.x, is = blockIdx.y;
    const int t = threadIdx.x;
    float cl[5];
    float m = -3.4e38f;
    #pragma unroll
    for (int k = 0; k < 5; ++k) {
        int i = t + k * 256;
        cl[k] = (i < IC) ? cvec[i] : -3.4e38f;
        m = fmaxf(m, cl[k]);
    }
    float M = blockReduceMax<256>(m, red);
    float z = 0;
    #pragma unroll
    for (int k = 0; k < 5; ++k) {
        int i = t + k * 256;
        if (i < IC) { float e = expf(cl[k] - M); eS[i] = e; z += e; }
    }
    float Z = blockReduceSum<256>(z, red);
    const float invZ = 1.0f / Z;
    const int i0 = is * (IC / SPLITS);
    float2 acc = make_float2(0.f, 0.f);
    const float2* xp = reinterpret_cast<const float2*>(x + ((size_t)b * IC + i0) * CH) + t;
    #pragma unroll 4
    for (int i = i0; i < i0 + IC / SPLITS; ++i) {
        float w = eS[i];
        float2 xv = *xp;
        acc.x += w * xv.x;
        acc.y += w * xv.y;
        xp += CH / 2;
    }
    float2* outp = reinterpret_cast<float2*>(xcpart + ((size_t)(is * B + b)) * CH) + t;
    *outp = make_float2(acc.x * invZ, acc.y * invZ);
}

__global__ __launch_bounds__(1024) void k_core_f(const float* __restrict__ xcpart,
                                                 const float* __restrict__ WWT,
                                                 const float* __restrict__ Wb,
                                                 const float* __restrict__ bbp,
                                                 float* __restrict__ Wv) {
    __shared__ float xcS[CH];
    __shared__ float hS[CH];
    __shared__ float red[16];
    __shared__ float gS;
    const int b = blockIdx.x, tid = threadIdx.x;
    const int c = tid & (CH - 1), half = tid >> 9;
    if (half == 0) {
        float s = 0;
        #pragma unroll
        for (int is = 0; is < SPLITS; ++is) s += xcpart[((size_t)(is * B + b)) * CH + c];
        xcS[c] = s;
    }
    __syncthreads();
    float acc = 0;
    const int cp0 = half * (CH / 2);
    for (int cp = cp0; cp < cp0 + CH / 2; ++cp)
        acc += xcS[cp] * WWT[(size_t)cp * CH + c];
    if (half == 0) hS[c] = acc;
    __syncthreads();
    if (half == 1) hS[c] += acc;
    __syncthreads();
    float part = 0;
    if (half == 0) {
        float xcv = xcS[c];
        part = xcv * hS[c] + 2.0f * Wb[c] * xcv;
    }
    float tot = blockReduceSum<1024>(part, red);
    if (tid == 0) {
        float n2 = tot + *bbp;
        float n = sqrtf(n2);
        gS = n / (1.0f + n2);
    }
    __syncthreads();
    if (half == 0) Wv[(size_t)b * CH + c] = gS * (hS[c] + Wb[c]);
}

__global__ __launch_bounds__(256) void k_passC_f32(const float* __restrict__ x,
                                                   const float* __restrict__ Wv,
                                                   float* __restrict__ cvec) {
    __shared__ float red[4];
    const int i = blockIdx.x, t = threadIdx.x;
    float acc = 0;
    const float2* wvp = reinterpret_cast<const float2*>(Wv) + t;
    const float2* xp = reinterpret_cast<const float2*>(x) + (size_t)i * (CH / 2) + t;
    #pragma unroll 4
    for (int b = 0; b < B; ++b) {
        float2 xv = xp[(size_t)b * IC * (CH / 2)];
        float2 wv = wvp[(size_t)b * (CH / 2)];
        acc += xv.x * wv.x + xv.y * wv.y;
    }
    float tot = blockReduceSum<256>(acc, red);
    if (t == 0) cvec[i] += tot;
}

__global__ __launch_bounds__(512) void k_final_f(const float* __restrict__ xcpart,
                                                 const float* __restrict__ W,
                                                 const float* __restrict__ bias,
                                                 float* __restrict__ out) {
    __shared__ float xcS[CH];
    __shared__ float red[8];
    __shared__ float gS;
    const int b = blockIdx.x, j = threadIdx.x;
    float s = 0;
    #pragma unroll
    for (int is = 0; is < SPLITS; ++is) s += xcpart[((size_t)(is * B + b)) * CH + j];
    xcS[j] = s;
    __syncthreads();
    float sj = bias[j];
    for (int c = 0; c < CH; ++c) sj += xcS[c] * W[(size_t)c * CH + j];
    float n2 = blockReduceSum<512>(sj * sj, red);
    if (j == 0) { float n = sqrtf(n2); gS = n / (1.0f + n2); }
    __syncthreads();
    out[(size_t)b * CH + j] = sj * gS;
}

// ---------------- launch ----------------

extern "C" void kernel_launch(void* const* d_in, const int* in_sizes, int n_in,
                              void* d_out, int out_size, void* d_ws, size_t ws_size,
                              hipStream_t stream) {
    (void)in_sizes; (void)n_in; (void)out_size;
    const float* x      = (const float*)d_in[0];   // [64,1152,512]
    const float* W      = (const float*)d_in[1];   // [512,512]  (in,out)
    const float* bias   = (const float*)d_in[2];   // [512]
    const float* coeffs = (const float*)d_in[3];   // [1,1152,1]
    float* out = (float*)d_out;

    const size_t xbf_bytes = (size_t)B * IC * CH * 2;   // 75.5 MB
    const size_t fast_floats = 262144 + 512 + 16 + 10 * IC + 64;
    const bool fast = ws_size >= xbf_bytes + fast_floats * 4 + 256;

    if (fast) {
        uint4* xbf = (uint4*)d_ws;
        float* ws  = (float*)((char*)d_ws + xbf_bytes);
        float* WWT  = ws;                    // 262144
        float* Wb   = ws + 262144;           // 512
        float* bb   = ws + 262656;           // 16
        float* bufs = ws + 262672;           // 10*1152

        k_setup<<<NCVT + 1024 + 3, 256, 0, stream>>>(x, W, bias, coeffs,
                                                     xbf, WWT, Wb, bb, bufs);
        for (int t = 0; t < 9; ++t)
            k_iter<<<B, 1024, 0, stream>>>(xbf, WWT, Wb, bb,
                                           bufs + (size_t)t * IC,
                                           bufs + (size_t)(t + 1) * IC);
        k_final<<<B, 1024, 0, stream>>>(xbf, W, bias, bufs + (size_t)9 * IC, out);
    } else {
        float* ws = (float*)d_ws;
        float* WT     = ws;              // 262144
        float* WWT    = ws + 262144;     // 262144
        float* Wb     = ws + 524288;     // 512
        float* bb     = ws + 524800;     // 16
        float* cvec   = ws + 524816;     // 1152
        float* Wv     = ws + 525968;     // 32768
        float* xcpart = ws + 558736;     // 524288

        k_transpose<<<dim3(16, 16), dim3(32, 32), 0, stream>>>(W, WT);
        k_wwt_f<<<256, 256, 0, stream>>>(W, WT, WWT);
        k_wb_f<<<1, 512, 0, stream>>>(WT, bias, Wb, bb);
        k_init_f<<<5, 256, 0, stream>>>(coeffs, cvec);
        for (int t = 0; t < 9; ++t) {
            k_passA_f32<<<dim3(B, SPLITS), 256, 0, stream>>>(x, cvec, xcpart);
            k_core_f<<<B, 1024, 0, stream>>>(xcpart, WWT, Wb, bb, Wv);
            k_passC_f32<<<IC, 256, 0, stream>>>(x, Wv, cvec);
        }
        k_passA_f32<<<dim3(B, SPLITS), 256, 0, stream>>>(x, cvec, xcpart);
        k_final_f<<<B, 512, 0, stream>>>(xcpart, W, bias, out);
    }
}